// Round 1
// baseline (147.475 us; speedup 1.0000x reference)
//
#include <hip/hip_runtime.h>
#include <cmath>

// Problem constants (LowRankExperts)
constexpr int kE = 16;
constexpr int kB = 1024;
constexpr int kI = 512;
constexpr int kH = 16;
constexpr int kF = 8192;           // I*R + R*O
constexpr int kAH = 4096;          // I*R (first half of f -> A)
constexpr long long kATOT = (long long)kE * kB * kAH;  // 67108864 floats in A

// ---------------------------------------------------------------------------
// Kernel A: h[e*B+b][hh] = tanh(dot(x[b,:], W1[e,:,hh]) + b1[e][hh])
// grid: (B/16, E), block: 256 = 16 b-rows x 16 hh
// x tile staged in LDS (padded stride 520 floats -> distinct banks per row
// group, 16B-aligned rows); W1 read from global (32KB per expert, L1-resident,
// wave-broadcast since all 4 row-groups read the same 64B segment).
// ---------------------------------------------------------------------------
__global__ __launch_bounds__(256) void k_hidden(const float* __restrict__ x,
                                                const float* __restrict__ W1,
                                                const float* __restrict__ b1,
                                                float* __restrict__ hws) {
  __shared__ float xs[16][520];
  const int e  = blockIdx.y;
  const int b0 = blockIdx.x * 16;
  const int tid = threadIdx.x;

  // Stage 16 x-rows (16*512 floats, contiguous in global) as float4.
  const float4* xg = (const float4*)(x + (size_t)b0 * kI);
#pragma unroll
  for (int k = 0; k < 8; ++k) {
    int idx = tid + k * 256;            // float4 index 0..2047
    float4 v = xg[idx];
    int row = idx >> 7;                 // 128 float4 per row
    int col = (idx & 127) << 2;
    *(float4*)&xs[row][col] = v;        // row stride 2080B: 16B aligned
  }
  __syncthreads();

  const int hh = tid & 15;
  const int bl = tid >> 4;
  const float* w1e = W1 + (size_t)e * kI * kH + hh;

  float acc = 0.f;
#pragma unroll 8
  for (int i = 0; i < kI; ++i) {
    acc = fmaf(xs[bl][i], w1e[i * kH], acc);
  }
  acc += b1[e * kH + hh];
  hws[(size_t)(e * kB + b0 + bl) * kH + hh] = tanhf(acc);
}

// ---------------------------------------------------------------------------
// Kernel B: f[e,b,j] = dot(h[e,b,:], W2[e,:,j]) + b2[e,j], split-written into
// the A region (j<4096) or Bf region (j>=4096) of d_out.
// grid: (B/32, F/512, E), block: 256 threads = 128 j-float4-cols x 2 b-halves.
// Each thread keeps its 16-deep W2 column slice in registers (64 VGPR) and
// sweeps 16 h-rows from LDS -> 16 coalesced float4 stores (1KB/wave/row).
// ---------------------------------------------------------------------------
__global__ __launch_bounds__(256) void k_factors(const float* __restrict__ hws,
                                                 const float* __restrict__ W2,
                                                 const float* __restrict__ b2,
                                                 float* __restrict__ out) {
  __shared__ float hs[32 * kH];  // 32 rows x 16 h
  const int e  = blockIdx.z;
  const int b0 = blockIdx.x * 32;
  const int j0 = blockIdx.y * 512;
  const int tid = threadIdx.x;

  // Stage h rows for this b-tile: 512 contiguous floats.
  if (tid < 128) {
    ((float4*)hs)[tid] = ((const float4*)(hws + (size_t)(e * kB + b0) * kH))[tid];
  }
  __syncthreads();

  const int jq   = tid & 127;     // float4 column within tile
  const int bsub = tid >> 7;      // 0..1 (wave-uniform)
  const int j    = j0 + jq * 4;

  // Load W2 column slice: 16 float4, register-resident.
  const float* w2ej = W2 + (size_t)e * kH * kF + j;
  float4 w[kH];
#pragma unroll
  for (int hh = 0; hh < kH; ++hh) w[hh] = *(const float4*)(w2ej + hh * kF);

  const float4 bias = *(const float4*)(b2 + (size_t)e * kF + j);

  // Destination base: A region or Bf region (each contiguous per (e,b)).
  float* dst;
  if (j0 < kAH) {
    dst = out + (size_t)(e * kB + b0) * (size_t)kAH + j;
  } else {
    dst = out + (size_t)kATOT + (size_t)(e * kB + b0) * (size_t)kAH + (j - kAH);
  }

  const float* hrow = hs + (bsub * 16) * kH;
#pragma unroll
  for (int rr = 0; rr < 16; ++rr) {
    const float4 h0 = *(const float4*)(hrow + rr * kH + 0);
    const float4 h1 = *(const float4*)(hrow + rr * kH + 4);
    const float4 h2 = *(const float4*)(hrow + rr * kH + 8);
    const float4 h3 = *(const float4*)(hrow + rr * kH + 12);
    float4 acc = bias;
#define FMA4(hv, idx)                                   \
    acc.x = fmaf(hv, w[idx].x, acc.x);                  \
    acc.y = fmaf(hv, w[idx].y, acc.y);                  \
    acc.z = fmaf(hv, w[idx].z, acc.z);                  \
    acc.w = fmaf(hv, w[idx].w, acc.w);
    FMA4(h0.x, 0)  FMA4(h0.y, 1)  FMA4(h0.z, 2)  FMA4(h0.w, 3)
    FMA4(h1.x, 4)  FMA4(h1.y, 5)  FMA4(h1.z, 6)  FMA4(h1.w, 7)
    FMA4(h2.x, 8)  FMA4(h2.y, 9)  FMA4(h2.z, 10) FMA4(h2.w, 11)
    FMA4(h3.x, 12) FMA4(h3.y, 13) FMA4(h3.z, 14) FMA4(h3.w, 15)
#undef FMA4
    *(float4*)(dst + (size_t)(bsub * 16 + rr) * (size_t)kAH) = acc;
  }
}

extern "C" void kernel_launch(void* const* d_in, const int* in_sizes, int n_in,
                              void* d_out, int out_size, void* d_ws, size_t ws_size,
                              hipStream_t stream) {
  const float* x  = (const float*)d_in[0];
  const float* W1 = (const float*)d_in[1];
  const float* b1 = (const float*)d_in[2];
  const float* W2 = (const float*)d_in[3];
  const float* b2 = (const float*)d_in[4];
  float* out = (float*)d_out;
  float* hws = (float*)d_ws;  // E*B*H floats = 1 MB

  k_hidden<<<dim3(kB / 16, kE), 256, 0, stream>>>(x, W1, b1, hws);
  k_factors<<<dim3(kB / 32, kF / 512, kE), 256, 0, stream>>>(hws, W2, b2, out);
}

// Round 2
// 130.814 us; speedup vs baseline: 1.1274x; 1.1274x over previous
//
#include <hip/hip_runtime.h>
#include <cmath>

// Problem constants (LowRankExperts)
constexpr int kE = 16;
constexpr int kB = 1024;
constexpr int kI = 512;
constexpr int kH = 16;
constexpr int kF = 8192;           // I*R + R*O
constexpr int kAH = 4096;          // I*R (first half of f -> A)
constexpr long long kATOT = (long long)kE * kB * kAH;  // 67108864 floats in A

typedef float f32x4 __attribute__((ext_vector_type(4)));

// ---------------------------------------------------------------------------
// Kernel A: h[e*B+b][hh] = tanh(dot(x[b,:], W1[e,:,hh]) + b1[e][hh])
// grid: (B/16, E), block: 256 = 16 b-rows x 16 hh
// ---------------------------------------------------------------------------
__global__ __launch_bounds__(256) void k_hidden(const float* __restrict__ x,
                                                const float* __restrict__ W1,
                                                const float* __restrict__ b1,
                                                float* __restrict__ hws) {
  __shared__ float xs[16][520];
  const int e  = blockIdx.y;
  const int b0 = blockIdx.x * 16;
  const int tid = threadIdx.x;

  // Stage 16 x-rows (16*512 floats, contiguous in global) as float4.
  const float4* xg = (const float4*)(x + (size_t)b0 * kI);
#pragma unroll
  for (int k = 0; k < 8; ++k) {
    int idx = tid + k * 256;            // float4 index 0..2047
    float4 v = xg[idx];
    int row = idx >> 7;                 // 128 float4 per row
    int col = (idx & 127) << 2;
    *(float4*)&xs[row][col] = v;        // row stride 2080B: 16B aligned
  }
  __syncthreads();

  const int hh = tid & 15;
  const int bl = tid >> 4;
  const float* w1e = W1 + (size_t)e * kI * kH + hh;

  float acc = 0.f;
#pragma unroll 8
  for (int i = 0; i < kI; ++i) {
    acc = fmaf(xs[bl][i], w1e[i * kH], acc);
  }
  acc += b1[e * kH + hh];
  hws[(size_t)(e * kB + b0 + bl) * kH + hh] = tanhf(acc);
}

// ---------------------------------------------------------------------------
// Kernel B: f[e,b,j] = dot(h[e,b,:], W2[e,:,j]) + b2[e,j], split-written into
// the A region (j<4096) or Bf region (j>=4096) of d_out via NON-TEMPORAL
// stores (keeps L2 free to hold W2).
// grid: (B/32, F/1024, E), block: 256 threads = 256 distinct j-float4-cols.
// Each thread keeps its 16-deep W2 column slice in registers (64 VGPR) and
// sweeps all 32 h-rows from LDS -> 32 coalesced 1KB/wave nt-stores.
// W2 read per block: 16 KB (no duplication).
// ---------------------------------------------------------------------------
__global__ __launch_bounds__(256) void k_factors(const float* __restrict__ hws,
                                                 const float* __restrict__ W2,
                                                 const float* __restrict__ b2,
                                                 float* __restrict__ out) {
  __shared__ float hs[32 * kH];  // 32 rows x 16 h = 2 KB
  const int e  = blockIdx.z;
  const int b0 = blockIdx.x * 32;
  const int j0 = blockIdx.y * 1024;
  const int tid = threadIdx.x;

  // Stage h rows for this b-tile: 512 contiguous floats.
  if (tid < 128) {
    ((float4*)hs)[tid] = ((const float4*)(hws + (size_t)(e * kB + b0) * kH))[tid];
  }
  __syncthreads();

  const int j = j0 + tid * 4;     // this thread's 4 output columns

  // Load W2 column slice: 16 float4, register-resident (L2-served).
  const float* w2ej = W2 + (size_t)e * kH * kF + j;
  float4 w[kH];
#pragma unroll
  for (int hh = 0; hh < kH; ++hh) w[hh] = *(const float4*)(w2ej + hh * kF);

  const float4 bias = *(const float4*)(b2 + (size_t)e * kF + j);

  // Destination base: A region or Bf region (tile never straddles: 1024|4096).
  float* dst;
  if (j0 < kAH) {
    dst = out + (size_t)(e * kB + b0) * (size_t)kAH + j;
  } else {
    dst = out + (size_t)kATOT + (size_t)(e * kB + b0) * (size_t)kAH + (j - kAH);
  }

#pragma unroll 8
  for (int rr = 0; rr < 32; ++rr) {
    const float4 h0 = *(const float4*)(hs + rr * kH + 0);
    const float4 h1 = *(const float4*)(hs + rr * kH + 4);
    const float4 h2 = *(const float4*)(hs + rr * kH + 8);
    const float4 h3 = *(const float4*)(hs + rr * kH + 12);
    float4 acc = bias;
#define FMA4(hv, idx)                                   \
    acc.x = fmaf(hv, w[idx].x, acc.x);                  \
    acc.y = fmaf(hv, w[idx].y, acc.y);                  \
    acc.z = fmaf(hv, w[idx].z, acc.z);                  \
    acc.w = fmaf(hv, w[idx].w, acc.w);
    FMA4(h0.x, 0)  FMA4(h0.y, 1)  FMA4(h0.z, 2)  FMA4(h0.w, 3)
    FMA4(h1.x, 4)  FMA4(h1.y, 5)  FMA4(h1.z, 6)  FMA4(h1.w, 7)
    FMA4(h2.x, 8)  FMA4(h2.y, 9)  FMA4(h2.z, 10) FMA4(h2.w, 11)
    FMA4(h3.x, 12) FMA4(h3.y, 13) FMA4(h3.z, 14) FMA4(h3.w, 15)
#undef FMA4
    f32x4 v; v.x = acc.x; v.y = acc.y; v.z = acc.z; v.w = acc.w;
    __builtin_nontemporal_store(v, (f32x4*)(dst + (size_t)rr * (size_t)kAH));
  }
}

extern "C" void kernel_launch(void* const* d_in, const int* in_sizes, int n_in,
                              void* d_out, int out_size, void* d_ws, size_t ws_size,
                              hipStream_t stream) {
  const float* x  = (const float*)d_in[0];
  const float* W1 = (const float*)d_in[1];
  const float* b1 = (const float*)d_in[2];
  const float* W2 = (const float*)d_in[3];
  const float* b2 = (const float*)d_in[4];
  float* out = (float*)d_out;
  float* hws = (float*)d_ws;  // E*B*H floats = 1 MB

  k_hidden<<<dim3(kB / 16, kE), 256, 0, stream>>>(x, W1, b1, hws);
  k_factors<<<dim3(kB / 32, kF / 1024, kE), 256, 0, stream>>>(hws, W2, b2, out);
}